// Round 5
// baseline (270.426 us; speedup 1.0000x reference)
//
#include <hip/hip_runtime.h>

// Problem constants (fixed by reference):
//   N=16384 spatial, R=16 feat, P=4096 blocks, T=64 out-feat, B=8 batch
#define C_N 16384
#define C_R 16
#define C_P 4096
#define C_B 8

// One wave per block p; 4 waves (4 p's) per 256-thread WG; ZERO barriers.
// Each wave stages its own 4 KB x slice (same-wave LDS visibility needs no
// barrier) and runs a register double-buffered K-loop: issue chunk k+1's 32
// weight loads, then compute chunk k. First use of chunk k waits vmcnt(32),
// so chunk k+1 stays in flight; 16 independent waves/CU stagger their phases
// -> continuous HBM request stream (R3's barrier convoyed all waves into
// burst/silence cycles at 1.7 TB/s).
// R2's version of this spilled because `cur = cond ? buf1 : buf0` defeated
// SROA; here the two buffers are distinct named arrays only ever indexed by
// compile-time constants through force-inlined lambdas.
__global__ __launch_bounds__(256, 4)
void butterfly_local_conv(const float* __restrict__ x,
                          const float* __restrict__ Wrr,
                          const float* __restrict__ Wri,
                          const float* __restrict__ Wir,
                          const float* __restrict__ Wii,
                          const int*   __restrict__ perm,
                          float* __restrict__ out)
{
    __shared__ float xs[4][2][C_B][64];   // per-wave private x: [w][c][b][i], 16 KB/WG

    const int t    = threadIdx.x;
    const int w    = t >> 6;              // wave id = local p
    const int lane = t & 63;              // output column o
    const int p    = blockIdx.x * 4 + w;

    // ---- stage this wave's x slice (no barrier: same-wave produce/consume)
    {
        const int sc = lane >> 5;         // 0..1 (re/im)
        const int sb = (lane >> 2) & 7;   // 0..7 (batch)
        const int ss = lane & 3;          // 0..3 (window pos)
        const int n  = perm[4 * p + ss];
        const float4* xsrc = (const float4*)(x + (((size_t)(sb * 2 + sc)) * C_N + n) * C_R);
        const float4 v0 = xsrc[0], v1 = xsrc[1], v2 = xsrc[2], v3 = xsrc[3];
        float4* dst = (float4*)(&xs[w][sc][sb][ss * 16]);
        dst[0] = v0; dst[1] = v1; dst[2] = v2; dst[3] = v3;
    }

    const size_t wbase = (size_t)p * 64 * 64 + lane;
    const float* __restrict__ prr = Wrr + wbase;
    const float* __restrict__ pri = Wri + wbase;
    const float* __restrict__ pir = Wir + wbase;
    const float* __restrict__ pii = Wii + wbase;

    float acc_re[C_B], acc_im[C_B];
    #pragma unroll
    for (int b = 0; b < C_B; ++b) { acc_re[b] = 0.0f; acc_im[b] = 0.0f; }

    float bufA[32], bufB[32];   // ping-pong weight chunks (8 i-rows x 4 mats)

    auto load_chunk = [&](float (&buf)[32], int i0) __attribute__((always_inline)) {
        #pragma unroll
        for (int k = 0; k < 8; ++k) {
            buf[k]      = prr[(i0 + k) * 64];
            buf[8 + k]  = pri[(i0 + k) * 64];
            buf[16 + k] = pir[(i0 + k) * 64];
            buf[24 + k] = pii[(i0 + k) * 64];
        }
    };
    auto compute_chunk = [&](float (&buf)[32], int i0) __attribute__((always_inline)) {
        #pragma unroll
        for (int b = 0; b < C_B; ++b) {
            float xr[8], xi[8];
            *(float4*)&xr[0] = *(const float4*)(&xs[w][0][b][i0]);
            *(float4*)&xr[4] = *(const float4*)(&xs[w][0][b][i0 + 4]);
            *(float4*)&xi[0] = *(const float4*)(&xs[w][1][b][i0]);
            *(float4*)&xi[4] = *(const float4*)(&xs[w][1][b][i0 + 4]);
            #pragma unroll
            for (int k = 0; k < 8; ++k) {
                acc_re[b] = fmaf(xr[k], buf[k],      acc_re[b]);
                acc_re[b] = fmaf(xi[k], buf[8 + k],  acc_re[b]);
                acc_im[b] = fmaf(xr[k], buf[16 + k], acc_im[b]);
                acc_im[b] = fmaf(xi[k], buf[24 + k], acc_im[b]);
            }
        }
    };

    // ---- software pipeline over 8 chunks, fully unrolled, no pointer swaps
    load_chunk(bufA, 0);
    #pragma unroll
    for (int cp = 0; cp < 4; ++cp) {
        load_chunk(bufB, cp * 16 + 8);          // prefetch odd chunk
        compute_chunk(bufA, cp * 16);           // consume even chunk
        if (cp < 3) load_chunk(bufA, cp * 16 + 16);  // prefetch next even
        compute_chunk(bufB, cp * 16 + 8);       // consume odd chunk
    }

    // ---- epilogue: 16 coalesced 256 B stores
    const size_t obase = (size_t)p * 64 + lane;
    #pragma unroll
    for (int b = 0; b < C_B; ++b) {
        out[((size_t)(b * 2 + 0)) * (C_N * C_R) + obase] = acc_re[b];
        out[((size_t)(b * 2 + 1)) * (C_N * C_R) + obase] = acc_im[b];
    }
}

extern "C" void kernel_launch(void* const* d_in, const int* in_sizes, int n_in,
                              void* d_out, int out_size, void* d_ws, size_t ws_size,
                              hipStream_t stream) {
    const float* x    = (const float*)d_in[0];
    const float* Wrr  = (const float*)d_in[1];
    const float* Wri  = (const float*)d_in[2];
    const float* Wir  = (const float*)d_in[3];
    const float* Wii  = (const float*)d_in[4];
    const int*   perm = (const int*)d_in[5];
    float* out = (float*)d_out;

    // 4 p's per 256-thread WG: grid 1024.
    butterfly_local_conv<<<dim3(C_P / 4), dim3(256), 0, stream>>>(
        x, Wrr, Wri, Wir, Wii, perm, out);
}

// Round 6
// 264.958 us; speedup vs baseline: 1.0206x; 1.0206x over previous
//
#include <hip/hip_runtime.h>

// Problem constants (fixed by reference):
//   N=16384 spatial, R=16 feat, P=4096 blocks, T=64 out-feat, B=8 batch
#define C_N 16384
#define C_R 16
#define C_P 4096
#define C_B 8
#define XROW 65   // padded x row (65 floats) -> staging writes 2-way max (free)

// Wave-task = (p, component): comp=0 -> y_re from (Wrr,Wri), comp=1 -> y_im
// from (Wir,Wii). 8192 independent wave-tasks, 4 per 256-thread WG, ZERO
// barriers. Lane l owns output columns 4*(l&15)..+3 and row-group l>>4, so
// each weight load is global_load_dwordx4 (1 KB/wave contiguous -- the m13
// 6.3 TB/s pattern). K-loop: 16 chunks of 4 rows, TRIPLE-buffered in six
// NAMED float4s (wa0..wb2, no arrays -> nothing for the allocator to demote
// to scratch, the failure of R2/R5). Steady state keeps 6 dwordx4 loads in
// flight per wave; ~16-24 waves/CU x 6 KB >> the ~22 KB/CU needed for
// 6.3 TB/s. Epilogue: shfl_xor butterfly over row-groups, lanes 0-15 store.
__global__ __launch_bounds__(256, 4)
void butterfly_local_conv(const float* __restrict__ x,
                          const float* __restrict__ Wrr,
                          const float* __restrict__ Wri,
                          const float* __restrict__ Wir,
                          const float* __restrict__ Wii,
                          const int*   __restrict__ perm,
                          float* __restrict__ out)
{
    __shared__ float xs[4][2][C_B][XROW];   // per-wave private x, ~16.3 KB/WG

    const int t    = threadIdx.x;
    const int w    = t >> 6;
    const int l    = t & 63;
    const int task = blockIdx.x * 4 + w;
    const int p    = task >> 1;
    const int comp = task & 1;

    // ---- x tile loads first (oldest in vm queue)
    const int sc = l >> 5;            // 0..1 re/im component of x
    const int sb = (l >> 2) & 7;      // 0..7 batch
    const int ss = l & 3;             // 0..3 window position
    const int n  = perm[4 * p + ss];
    const float* xsrc = x + (((size_t)(sb * 2 + sc)) * C_N + n) * C_R;
    const float4 xv0 = *(const float4*)(xsrc);
    const float4 xv1 = *(const float4*)(xsrc + 4);
    const float4 xv2 = *(const float4*)(xsrc + 8);
    const float4 xv3 = *(const float4*)(xsrc + 12);

    // ---- weight pointers: lane's float4 = rows rg, columns 4*cq..+3
    const float* __restrict__ WA = comp ? Wir : Wrr;
    const float* __restrict__ WB = comp ? Wii : Wri;
    const int rg = l >> 4;            // row-group 0..3
    const int cq = l & 15;            // column-quad 0..15
    const float4* __restrict__ WA4 =
        (const float4*)(WA + (size_t)p * 4096 + rg * 64 + cq * 4);
    const float4* __restrict__ WB4 =
        (const float4*)(WB + (size_t)p * 4096 + rg * 64 + cq * 4);

    float4 wa0, wb0, wa1, wb1, wa2, wb2;

#define LOADC(S, C) do { wa##S = WA4[(C) * 64]; wb##S = WB4[(C) * 64]; } while (0)

    // prologue: 3 chunks in flight before anything waits
    LOADC(0, 0); LOADC(1, 1); LOADC(2, 2);

    // ---- commit x to LDS (waits the 4 x loads only; weight loads in flight)
    {
        float* dst = &xs[w][sc][sb][ss * 16];
        *(float4*)(dst)      = xv0;
        *(float4*)(dst + 4)  = xv1;
        *(float4*)(dst + 8)  = xv2;
        *(float4*)(dst + 12) = xv3;
    }

    float4 acc[C_B];
    #pragma unroll
    for (int b = 0; b < C_B; ++b) acc[b] = make_float4(0.f, 0.f, 0.f, 0.f);

    // xs[w][c][b][i] = xsr[c*8*XROW + b*XROW + i]; reads are 16-lane
    // broadcasts of 4 consecutive dwords -> conflict-free.
    const float* xsr = &xs[w][0][0][0];

#define COMPC(S, C) do {                                                   \
    const int ib = 4 * (C) + rg;                                           \
    _Pragma("unroll")                                                      \
    for (int b = 0; b < C_B; ++b) {                                        \
        const float xr = xsr[b * XROW + ib];                               \
        const float xi = xsr[C_B * XROW + b * XROW + ib];                  \
        acc[b].x = fmaf(xr, wa##S.x, acc[b].x);                            \
        acc[b].y = fmaf(xr, wa##S.y, acc[b].y);                            \
        acc[b].z = fmaf(xr, wa##S.z, acc[b].z);                            \
        acc[b].w = fmaf(xr, wa##S.w, acc[b].w);                            \
        acc[b].x = fmaf(xi, wb##S.x, acc[b].x);                            \
        acc[b].y = fmaf(xi, wb##S.y, acc[b].y);                            \
        acc[b].z = fmaf(xi, wb##S.z, acc[b].z);                            \
        acc[b].w = fmaf(xi, wb##S.w, acc[b].w);                            \
    }                                                                      \
} while (0)

    // ---- 16 chunks, slot = chunk % 3, prefetch distance 3 (manual unroll:
    // slot names must be compile-time identifiers)
    COMPC(0,  0); LOADC(0,  3);
    COMPC(1,  1); LOADC(1,  4);
    COMPC(2,  2); LOADC(2,  5);
    COMPC(0,  3); LOADC(0,  6);
    COMPC(1,  4); LOADC(1,  7);
    COMPC(2,  5); LOADC(2,  8);
    COMPC(0,  6); LOADC(0,  9);
    COMPC(1,  7); LOADC(1, 10);
    COMPC(2,  8); LOADC(2, 11);
    COMPC(0,  9); LOADC(0, 12);
    COMPC(1, 10); LOADC(1, 13);
    COMPC(2, 11); LOADC(2, 14);
    COMPC(0, 12); LOADC(0, 15);
    COMPC(1, 13);
    COMPC(2, 14);
    COMPC(0, 15);

    // ---- reduce over the 4 row-groups (lanes l, l^16, l^32, l^48)
    #pragma unroll
    for (int b = 0; b < C_B; ++b) {
        acc[b].x += __shfl_xor(acc[b].x, 16);
        acc[b].y += __shfl_xor(acc[b].y, 16);
        acc[b].z += __shfl_xor(acc[b].z, 16);
        acc[b].w += __shfl_xor(acc[b].w, 16);
        acc[b].x += __shfl_xor(acc[b].x, 32);
        acc[b].y += __shfl_xor(acc[b].y, 32);
        acc[b].z += __shfl_xor(acc[b].z, 32);
        acc[b].w += __shfl_xor(acc[b].w, 32);
    }

    // ---- store: lanes 0..15 write float4 -> 256 B contiguous per (b,comp)
    if (l < 16) {
        #pragma unroll
        for (int b = 0; b < C_B; ++b) {
            *(float4*)(out + ((size_t)(b * 2 + comp)) * (C_N * C_R)
                           + (size_t)p * 64 + l * 4) = acc[b];
        }
    }
}

extern "C" void kernel_launch(void* const* d_in, const int* in_sizes, int n_in,
                              void* d_out, int out_size, void* d_ws, size_t ws_size,
                              hipStream_t stream) {
    const float* x    = (const float*)d_in[0];
    const float* Wrr  = (const float*)d_in[1];
    const float* Wri  = (const float*)d_in[2];
    const float* Wir  = (const float*)d_in[3];
    const float* Wii  = (const float*)d_in[4];
    const int*   perm = (const int*)d_in[5];
    float* out = (float*)d_out;

    // 8192 wave-tasks (p x component), 4 per 256-thread WG -> 2048 WGs.
    butterfly_local_conv<<<dim3(C_P * 2 / 4), dim3(256), 0, stream>>>(
        x, Wrr, Wri, Wir, Wii, perm, out);
}